// Round 2
// baseline (96.021 us; speedup 1.0000x reference)
//
#include <hip/hip_runtime.h>
#include <math.h>

// Problem constants (from reference setup_inputs): B=4, N=8192, F=8192, P=2048
#define Bn 4
#define Nn 8192
#define Fn 8192
#define Pn 2048
#define PTS 32               // points per block
#define TPB 512              // threads per block
#define HALF 2048            // faces staged in LDS per pass (4 passes = Fn)
#define NPASS (Fn / HALF)
#define MIN_DIST 0.1f
#define FLTMAX_BITS 0x7F7FFFFFu

typedef float v2f __attribute__((ext_vector_type(2)));

struct Meta { float acc; int cnt; };

// Single fused kernel (standard launch, no grid.sync). Grid = Bn*64 = 256
// blocks (1/CU), 512 threads. Block (b,pg) owns 32 points and ALL 8192 faces:
//   - 4 passes: precompute 2048 faces -> (n*s, d*s) into 32KB LDS, where
//     d = MIN_DIST - dot(center,n), s = ||n||. signed' = dot(p,n*s)+d*s,
//     signed'^2 == ref sqdist (signed^2 * fn_sq), sign preserved.
//   - thread t: point pair q=t&15 (points 2q,2q+1, packed v_pk_fma_f32),
//     face slice t>>4 (64 faces/pass; LDS reads are 4 distinct float4 per
//     wave, 16-lane broadcast each -> conflict-free ds_read_b128).
//   - min tracked as raw fp32 bits with unsigned min: non-negative floats
//     order as uints; negative signed (bits >= 0x80000000) never beats the
//     FLT_MAX init => exactly where(signed<0,BIG) + all-negative "inside".
//   - cross-slice min via LDS reuse, per-block 32-point sum, then the
//     round-0-verified device-scope atomic ticket: atomicAdd(acc),
//     threadfence, atomicAdd(cnt); last block reads acc and writes out.
//     Meta is zeroed each iteration by a hipMemsetAsync graph node.
__global__ __launch_bounds__(TPB)
void fused_pfd(const float* __restrict__ V, const float* __restrict__ FN,
               const int* __restrict__ Fidx, const float* __restrict__ points,
               const unsigned char* __restrict__ flagsB,
               Meta* __restrict__ meta, float* __restrict__ out) {
    const int t  = threadIdx.x;
    const int b  = blockIdx.x >> 6;
    const int pg = blockIdx.x & 63;
    const int* flagsI = (const int*)flagsB;

    __shared__ float4 lf[HALF];          // 32 KB, re-purposed scratch via casts

    // --- storage-mode probe: exterior_flag may be byte bools (8KB) or int32
    // 0/1 (32KB). Read first 512 ints (2KB, in-bounds for both). In int mode
    // every value is 0/1; in byte mode 4 packed bools per int make a value >1
    // essentially certain (P(miss) ~ 2^-1536 over 1536 high bytes).
    int* scratch = (int*)lf;
    if (t == 0) scratch[0] = 0;
    __syncthreads();
    if (((unsigned)flagsI[t]) > 1u) scratch[0] = 1;   // benign write race
    __syncthreads();
    const int mode = scratch[0];                       // 1 => byte bools
    __syncthreads();                                   // scratch read done before staging overwrites

    // --- this thread's point pair: q = t&15 -> points 2q, 2q+1 ---
    const int q = t & 15, slice = t >> 4;
    const int p0 = pg * PTS + 2 * q;
    const float* pb = points + ((size_t)b * Pn + p0) * 3;
    v2f px = {pb[0], pb[3]};
    v2f py = {pb[1], pb[4]};
    v2f pz = {pb[2], pb[5]};
    unsigned m0 = FLTMAX_BITS, m1 = FLTMAX_BITS;

    const float* Vb = V + (size_t)b * Nn * 3;

    for (int h = 0; h < NPASS; ++h) {
        // --- precompute 2048 faces into LDS (4 per thread, coalesced idx) ---
#pragma unroll 4
        for (int j = 0; j < HALF / TPB; ++j) {
            int fl = j * TPB + t;
            size_t fb = ((size_t)b * Fn + h * HALF + fl) * 3;
            int i0 = Fidx[fb + 0], i1 = Fidx[fb + 1], i2 = Fidx[fb + 2];
            float cx = (Vb[i0*3+0] + Vb[i1*3+0] + Vb[i2*3+0]) * (1.0f/3.0f);
            float cy = (Vb[i0*3+1] + Vb[i1*3+1] + Vb[i2*3+1]) * (1.0f/3.0f);
            float cz = (Vb[i0*3+2] + Vb[i1*3+2] + Vb[i2*3+2]) * (1.0f/3.0f);
            float nx = FN[fb + 0], ny = FN[fb + 1], nz = FN[fb + 2];
            float d  = MIN_DIST - (cx*nx + cy*ny + cz*nz);
            float s  = sqrtf(nx*nx + ny*ny + nz*nz);
            lf[fl] = make_float4(nx*s, ny*s, nz*s, d*s);
        }
        __syncthreads();

        // --- 64 faces for this thread this pass: local face = i*32 + slice ---
#pragma unroll 8
        for (int i = 0; i < HALF / 32; ++i) {
            float4 f = lf[i * 32 + slice];
            v2f fx = {f.x, f.x}, fy = {f.y, f.y}, fz = {f.z, f.z}, fw = {f.w, f.w};
#if __has_builtin(__builtin_elementwise_fma)
            v2f s = __builtin_elementwise_fma(px, fx,
                    __builtin_elementwise_fma(py, fy,
                    __builtin_elementwise_fma(pz, fz, fw)));
#else
            v2f s;
            s.x = fmaf(px.x, f.x, fmaf(py.x, f.y, fmaf(pz.x, f.z, f.w)));
            s.y = fmaf(px.y, f.x, fmaf(py.y, f.y, fmaf(pz.y, f.z, f.w)));
#endif
            unsigned sx = __float_as_uint(s.x);
            unsigned sy = __float_as_uint(s.y);
            m0 = sx < m0 ? sx : m0;
            m1 = sy < m1 ? sy : m1;
        }
        __syncthreads();   // LDS dead before next pass overwrites
    }

    // --- cross-slice min: red[2*t+c] holds point (2*(t&15)+c) of slice t>>4 ---
    unsigned* red = (unsigned*)lf;
    red[2 * t + 0] = m0;
    red[2 * t + 1] = m1;
    __syncthreads();

    float val = 0.0f;
    if (t < 32) {                        // thread t owns local point t
        unsigned mm = FLTMAX_BITS;
#pragma unroll
        for (int s2 = 0; s2 < 32; ++s2) {
            unsigned v = red[(s2 * 16 + (t >> 1)) * 2 + (t & 1)];
            mm = v < mm ? v : mm;
        }
        int gp = b * Pn + pg * PTS + t;
        int ext = mode ? (flagsB[gp] != 0) : (flagsI[gp] != 0);
        float mf = __uint_as_float(mm);
        // mm == FLT_MAX bits -> no face with signed >= 0 -> "inside" -> 0
        val = (ext && mm < FLTMAX_BITS) ? mf * mf : 0.0f;
    }
    if (t < 64) {                        // wave 0: sum lanes 0..31 into lane 0
        for (int o = 16; o > 0; o >>= 1) val += __shfl_down(val, o);
    }

    if (t == 0) {
        atomicAdd(&meta->acc, val);
        __threadfence();
        int ticket = atomicAdd(&meta->cnt, 1);
        if (ticket == (int)gridDim.x - 1) {
            // all blocks' acc-adds are fenced before their cnt-add -> visible
            float total = atomicAdd(&meta->acc, 0.0f);   // atomic read
            out[0] = total * (1.0f / (Bn * Pn));         // mean over P then B
        }
    }
}

extern "C" void kernel_launch(void* const* d_in, const int* in_sizes, int n_in,
                              void* d_out, int out_size, void* d_ws, size_t ws_size,
                              hipStream_t stream) {
    const float* mesh_V  = (const float*)d_in[0];
    const float* points  = (const float*)d_in[1];
    const float* mesh_FN = (const float*)d_in[2];
    const int*   mesh_F  = (const int*)d_in[3];
    const unsigned char* eflag = (const unsigned char*)d_in[4];
    float* out  = (float*)d_out;
    Meta*  meta = (Meta*)d_ws;

    hipMemsetAsync(meta, 0, sizeof(Meta), stream);   // graph-capturable node
    fused_pfd<<<Bn * 64, TPB, 0, stream>>>(mesh_V, mesh_FN, mesh_F, points,
                                           eflag, meta, out);
}

// Round 3
// 82.168 us; speedup vs baseline: 1.1686x; 1.1686x over previous
//
#include <hip/hip_runtime.h>
#include <math.h>

// Problem constants (from reference setup_inputs): B=4, N=8192, F=8192, P=2048
#define Bn 4
#define Nn 8192
#define Fn 8192
#define Pn 2048
#define G 64                 // face chunk-groups per batch
#define CH (Fn / G)          // 128 faces per block (precomputed exactly once)
#define TPB 512
#define PPT (Pn / TPB)       // 4 points per thread
#define MIN_DIST 0.1f
#define INIT_BITS 0x7F7F7F7Fu   // memset(0x7F) pattern; > any real sqdist bits

typedef float v2f __attribute__((ext_vector_type(2)));

// Single kernel, round-0 decomposition + atomicMin join (no 2nd dispatch).
// Grid: Bn*G = 256 blocks, 512 threads. Block (b,g):
//  - threads 0..127 precompute the block's 128 faces -> (n*s, d*s) in LDS
//    (each face computed exactly once across the grid), where
//    d = MIN_DIST - dot(center,n), s = ||n||. signed' = dot(p,n*s)+d*s,
//    signed'^2 == ref sqdist (signed^2*fn_sq), sign preserved.
//  - each thread owns 4 points (2 packed float2 pairs -> v_pk_fma_f32),
//    min-tracks raw fp32 bits with unsigned min: non-negative floats order
//    as uints; negative signed (bits >= 0x80000000) never beats INIT_BITS,
//    which implements where(signed<0, BIG) + the all-negative "inside" case.
//  - per-point block result joined across the 64 face-groups via global
//    atomicMin on gmin[b*Pn+p] (32 KB, memset-poisoned to 0x7F7F7F7F).
//  - completion ticket: counter also starts at 0x7F7F7F7F (same memset);
//    last block (ticket == INIT+255) finalizes: flag probe, square, sum.
__global__ __launch_bounds__(TPB)
void fused_min(const float* __restrict__ V, const float* __restrict__ FN,
               const int* __restrict__ Fidx, const float* __restrict__ points,
               const unsigned char* __restrict__ flagsB,
               unsigned* __restrict__ gmin, unsigned* __restrict__ cnt,
               float* __restrict__ out) {
    const int g = blockIdx.x & (G - 1);
    const int b = blockIdx.x / G;
    const int t = threadIdx.x;
    const int* flagsI = (const int*)flagsB;

    __shared__ float4 lf[CH];        // 2 KB
    __shared__ int sticket;
    __shared__ int smode;
    __shared__ float wsum[TPB / 64];

    // --- face precompute: one face per thread, exactly once grid-wide ---
    if (t < CH) {
        int i = b * Fn + g * CH + t;
        const int* fi = Fidx + (size_t)i * 3;
        int i0 = fi[0], i1 = fi[1], i2 = fi[2];
        const float* Vb = V + (size_t)b * Nn * 3;
        float cx = (Vb[i0*3+0] + Vb[i1*3+0] + Vb[i2*3+0]) * (1.0f/3.0f);
        float cy = (Vb[i0*3+1] + Vb[i1*3+1] + Vb[i2*3+1]) * (1.0f/3.0f);
        float cz = (Vb[i0*3+2] + Vb[i1*3+2] + Vb[i2*3+2]) * (1.0f/3.0f);
        const float* n = FN + (size_t)i * 3;
        float nx = n[0], ny = n[1], nz = n[2];
        float d = MIN_DIST - (cx*nx + cy*ny + cz*nz);
        float s = sqrtf(nx*nx + ny*ny + nz*nz);
        lf[t] = make_float4(nx*s, ny*s, nz*s, d*s);
    }

    // --- this thread's 4 points as 2 packed float2 pairs (coalesced) ---
    v2f px[PPT/2], py[PPT/2], pz[PPT/2];
    const float* pb = points + (size_t)b * Pn * 3;
#pragma unroll
    for (int k = 0; k < PPT/2; ++k) {
        int p0 = t + 2 * TPB * k;
        int p1 = p0 + TPB;
        px[k] = (v2f){pb[p0*3+0], pb[p1*3+0]};
        py[k] = (v2f){pb[p0*3+1], pb[p1*3+1]};
        pz[k] = (v2f){pb[p0*3+2], pb[p1*3+2]};
    }
    unsigned m[PPT];
#pragma unroll
    for (int k = 0; k < PPT; ++k) m[k] = INIT_BITS;

    __syncthreads();

#pragma unroll 8
    for (int j = 0; j < CH; ++j) {
        float4 f = lf[j];
        v2f fx = (v2f){f.x, f.x}, fy = (v2f){f.y, f.y},
            fz = (v2f){f.z, f.z}, fw = (v2f){f.w, f.w};
#pragma unroll
        for (int k = 0; k < PPT/2; ++k) {
#if __has_builtin(__builtin_elementwise_fma)
            v2f s = __builtin_elementwise_fma(px[k], fx,
                    __builtin_elementwise_fma(py[k], fy,
                    __builtin_elementwise_fma(pz[k], fz, fw)));
#else
            v2f s;
            s.x = fmaf(px[k].x, f.x, fmaf(py[k].x, f.y, fmaf(pz[k].x, f.z, f.w)));
            s.y = fmaf(px[k].y, f.x, fmaf(py[k].y, f.y, fmaf(pz[k].y, f.z, f.w)));
#endif
            unsigned sx = __float_as_uint(s.x);
            unsigned sy = __float_as_uint(s.y);
            m[2*k]   = sx < m[2*k]   ? sx : m[2*k];
            m[2*k+1] = sy < m[2*k+1] ? sy : m[2*k+1];
        }
    }

    // --- join across face-groups: coalesced atomicMin on fp32 bits ---
    unsigned* gb = gmin + (size_t)b * Pn;
#pragma unroll
    for (int k = 0; k < PPT/2; ++k) {
        atomicMin(&gb[t + 2 * TPB * k],       m[2*k]);
        atomicMin(&gb[t + 2 * TPB * k + TPB], m[2*k+1]);
    }

    // --- completion ticket (syncthreads drains this block's atomics first) ---
    __syncthreads();
    if (t == 0) {
        __threadfence();
        unsigned ticket = atomicAdd(cnt, 1u);
        sticket = (ticket == INIT_BITS + (unsigned)(Bn * G) - 1u);
    }
    __syncthreads();
    if (!sticket) return;
    __threadfence();     // acquire side before reading other blocks' mins

    // --- finalize (one block): flag-mode probe, per-point value, sum ---
    // exterior_flag may be byte bools (8KB) or int32 0/1 (32KB). Read first
    // 512 ints (2KB, in-bounds for both). In int mode all values are 0/1; in
    // byte mode packed bools make a value >1 essentially certain.
    if (t == 0) smode = 0;
    __syncthreads();
    if (((unsigned)flagsI[t]) > 1u) smode = 1;   // benign write race
    __syncthreads();
    const int mode = smode;

    float sum = 0.0f;
    for (int i = t; i < Bn * Pn; i += TPB) {
        // agent-scope load: bypass L1 so other blocks' L2 atomics are seen
        unsigned mm = __hip_atomic_load(&gmin[i], __ATOMIC_RELAXED,
                                        __HIP_MEMORY_SCOPE_AGENT);
        int ext = mode ? (flagsB[i] != 0) : (flagsI[i] != 0);
        float mf = __uint_as_float(mm);
        // mm == INIT_BITS -> no face with signed >= 0 -> "inside" -> 0
        if (ext && mm < INIT_BITS) sum += mf * mf;
    }
    for (int o = 32; o > 0; o >>= 1) sum += __shfl_down(sum, o);
    const int lane = t & 63, wid = t >> 6;
    if (lane == 0) wsum[wid] = sum;
    __syncthreads();
    if (t == 0) {
        float total = 0.0f;
#pragma unroll
        for (int w = 0; w < TPB / 64; ++w) total += wsum[w];
        out[0] = total * (1.0f / (Bn * Pn));   // mean over P then B
    }
}

extern "C" void kernel_launch(void* const* d_in, const int* in_sizes, int n_in,
                              void* d_out, int out_size, void* d_ws, size_t ws_size,
                              hipStream_t stream) {
    const float* mesh_V  = (const float*)d_in[0];
    const float* points  = (const float*)d_in[1];
    const float* mesh_FN = (const float*)d_in[2];
    const int*   mesh_F  = (const int*)d_in[3];
    const unsigned char* eflag = (const unsigned char*)d_in[4];
    float* out = (float*)d_out;

    unsigned* gmin = (unsigned*)d_ws;                 // Bn*Pn = 32 KB
    unsigned* cnt  = (unsigned*)((char*)d_ws + (size_t)Bn * Pn * sizeof(unsigned));

    // One small poison: gmin entries AND ticket counter all become 0x7F7F7F7F
    hipMemsetAsync(d_ws, 0x7F, (size_t)Bn * Pn * sizeof(unsigned) + sizeof(unsigned),
                   stream);
    fused_min<<<Bn * G, TPB, 0, stream>>>(mesh_V, mesh_FN, mesh_F, points,
                                          eflag, gmin, cnt, out);
}

// Round 4
// 75.206 us; speedup vs baseline: 1.2768x; 1.0926x over previous
//
#include <hip/hip_runtime.h>
#include <math.h>

// Problem constants (from reference setup_inputs): B=4, N=8192, F=8192, P=2048
#define Bn 4
#define Nn 8192
#define Fn 8192
#define Pn 2048
#define G 64                 // face chunk-groups per batch
#define CH (Fn / G)          // 128 faces per block
#define TPB 512              // threads per block (kernel 1)
#define PPT (Pn / TPB)       // 4 points per thread
#define MIN_DIST 0.1f
#define FLTMAX_BITS 0x7F7FFFFFu

typedef float v2f __attribute__((ext_vector_type(2)));

struct Meta { float acc; int cnt; int mode; };

// ---------------- Kernel 1: fused face-precompute + per-chunk point min -----
// Grid: Bn * G = 256 blocks, 512 threads.
// Block (b,g): precompute its CH=128 faces -> (n*s, d*s) in LDS, where
// d = MIN_DIST - dot(center,n), s = ||n||. Then signed' = dot(p,n*s)+d*s
// = s*(dot(p-c,n)+MIN_DIST), and signed'^2 == signed^2*fn_sq (ref sqdist),
// sign preserved. Each thread owns 4 points (2 float2 pairs -> v_pk_fma_f32)
// and min-tracks raw fp32 bits with unsigned min: non-negative floats order
// as uints; negative signed (bits >= 0x80000000) can never beat the FLT_MAX
// init, which exactly implements where(signed<0, BIG, .) + the all-negative
// ("inside") case. Block 0 additionally probes exterior_flag storage mode and
// zero-inits the Meta accumulator used by kernel 2.
__global__ __launch_bounds__(TPB)
void chunk_min(const float* __restrict__ V, const float* __restrict__ FN,
               const int* __restrict__ Fidx, const float* __restrict__ points,
               const unsigned char* __restrict__ flags,
               unsigned* __restrict__ partials, Meta* __restrict__ meta) {
    int g = blockIdx.x & (G - 1);
    int b = blockIdx.x / G;
    int tid = threadIdx.x;

    __shared__ float4 lf[CH];    // 2 KB

    // --- face precompute (threads 0..CH-1, one face each) ---
    if (tid < CH) {
        int i = b * Fn + g * CH + tid;
        const int* fi = Fidx + (size_t)i * 3;
        int i0 = fi[0], i1 = fi[1], i2 = fi[2];
        const float* Vb = V + (size_t)b * Nn * 3;
        float cx = (Vb[i0*3+0] + Vb[i1*3+0] + Vb[i2*3+0]) * (1.0f/3.0f);
        float cy = (Vb[i0*3+1] + Vb[i1*3+1] + Vb[i2*3+1]) * (1.0f/3.0f);
        float cz = (Vb[i0*3+2] + Vb[i1*3+2] + Vb[i2*3+2]) * (1.0f/3.0f);
        const float* n = FN + (size_t)i * 3;
        float nx = n[0], ny = n[1], nz = n[2];
        float d = MIN_DIST - (cx*nx + cy*ny + cz*nz);
        float s = sqrtf(nx*nx + ny*ny + nz*nz);
        lf[tid] = make_float4(nx*s, ny*s, nz*s, d*s);
    }

    // --- load this thread's 4 points as 2 (pair) float2 vectors ---
    // pair k covers points p0 = tid + 1024*k and p1 = p0 + 512
    v2f px[PPT/2], py[PPT/2], pz[PPT/2];
    const float* pb = points + (size_t)b * Pn * 3;
#pragma unroll
    for (int k = 0; k < PPT/2; ++k) {
        int p0 = tid + 2 * TPB * k;
        int p1 = p0 + TPB;
        px[k] = (v2f){pb[p0*3+0], pb[p1*3+0]};
        py[k] = (v2f){pb[p0*3+1], pb[p1*3+1]};
        pz[k] = (v2f){pb[p0*3+2], pb[p1*3+2]};
    }
    unsigned m[PPT];
#pragma unroll
    for (int k = 0; k < PPT; ++k) m[k] = FLTMAX_BITS;

    __syncthreads();

#pragma unroll 8
    for (int j = 0; j < CH; ++j) {
        float4 f = lf[j];
        v2f fx = (v2f){f.x, f.x}, fy = (v2f){f.y, f.y},
            fz = (v2f){f.z, f.z}, fw = (v2f){f.w, f.w};
#pragma unroll
        for (int k = 0; k < PPT/2; ++k) {
#if __has_builtin(__builtin_elementwise_fma)
            v2f s = __builtin_elementwise_fma(px[k], fx,
                    __builtin_elementwise_fma(py[k], fy,
                    __builtin_elementwise_fma(pz[k], fz, fw)));
#else
            v2f s;
            s.x = fmaf(px[k].x, f.x, fmaf(py[k].x, f.y, fmaf(pz[k].x, f.z, f.w)));
            s.y = fmaf(px[k].y, f.x, fmaf(py[k].y, f.y, fmaf(pz[k].y, f.z, f.w)));
#endif
            unsigned sx = __float_as_uint(s.x);
            unsigned sy = __float_as_uint(s.y);
            m[2*k]   = sx < m[2*k]   ? sx : m[2*k];
            m[2*k+1] = sy < m[2*k+1] ? sy : m[2*k+1];
        }
    }

    // partials layout: [g][b*Pn + p] so kernel 2 reads coalesced rows
    unsigned* out = partials + (size_t)g * (Bn * Pn) + (size_t)b * Pn;
#pragma unroll
    for (int k = 0; k < PPT/2; ++k) {
        out[tid + 2 * TPB * k]       = m[2*k];
        out[tid + 2 * TPB * k + TPB] = m[2*k+1];
    }

    // --- block 0 housekeeping: storage-mode probe + meta zero-init ---
    // exterior_flag is a jax bool array; it may arrive as 1-byte bool or as
    // int32 (0/1 little-endian). If int32, every byte at offset i%4!=0 is 0.
    // Bernoulli(0.5) over 8192 elems makes the probe essentially certain.
    if (blockIdx.x == 0) {
        __shared__ int cnt;
        if (tid == 0) cnt = 0;
        __syncthreads();
        int local = 0;
        for (int i = tid; i < Bn * Pn; i += TPB)
            if ((i & 3) && flags[i]) local++;
        if (local) atomicAdd(&cnt, local);
        __syncthreads();
        if (tid == 0) {
            meta->mode = (cnt > 0) ? 1 : 0;   // 1 -> byte bools, 0 -> int32
            meta->acc = 0.0f;
            meta->cnt = 0;
        }
    }
}

// ---------------- Kernel 2: per-point reduce + flag + global mean -----------
// Grid: 64 blocks x 128 threads (one thread per point). Min over G=64 partial
// rows (coalesced), apply exterior flag, square, block-reduce, then last-block
// ticket produces the final scalar (no extra launch).
__global__ __launch_bounds__(128)
void point_reduce(const unsigned* __restrict__ partials,
                  const unsigned char* __restrict__ flagsB,
                  const int* __restrict__ flagsI,
                  Meta* __restrict__ meta, float* __restrict__ out) {
    int i = blockIdx.x * 128 + threadIdx.x;   // 0 .. B*P-1
    unsigned m = FLTMAX_BITS;
#pragma unroll 8
    for (int c = 0; c < G; ++c) {
        unsigned v = partials[(size_t)c * (Bn * Pn) + i];
        m = v < m ? v : m;
    }
    int ext = (meta->mode) ? (flagsB[i] != 0) : (flagsI[i] != 0);
    float mf = __uint_as_float(m);
    // m == FLT_MAX bits -> no face had signed >= 0 -> "inside" -> 0 (ref match)
    float val = (ext && m < FLTMAX_BITS) ? mf * mf : 0.0f;

    // wave (64-lane) shuffle reduce, then across the 2 waves via LDS
    for (int o = 32; o > 0; o >>= 1) val += __shfl_down(val, o);
    __shared__ float wsum[2];
    int lane = threadIdx.x & 63, wid = threadIdx.x >> 6;
    if (lane == 0) wsum[wid] = val;
    __syncthreads();
    if (threadIdx.x == 0) {
        float s = wsum[0] + wsum[1];
        atomicAdd(&meta->acc, s);
        __threadfence();
        int ticket = atomicAdd(&meta->cnt, 1);
        if (ticket == gridDim.x - 1) {
            // all blocks' acc-adds are fenced before their cnt-add -> visible
            float total = atomicAdd(&meta->acc, 0.0f);  // atomic read
            out[0] = total * (1.0f / (Bn * Pn));  // mean over P then B
        }
    }
}

extern "C" void kernel_launch(void* const* d_in, const int* in_sizes, int n_in,
                              void* d_out, int out_size, void* d_ws, size_t ws_size,
                              hipStream_t stream) {
    const float* mesh_V  = (const float*)d_in[0];
    const float* points  = (const float*)d_in[1];
    const float* mesh_FN = (const float*)d_in[2];
    const int*   mesh_F  = (const int*)d_in[3];
    const void*  eflag   = d_in[4];
    float* out = (float*)d_out;

    char* ws = (char*)d_ws;
    const size_t partBytes = (size_t)G * Bn * Pn * sizeof(unsigned); // 2 MiB
    unsigned* partials = (unsigned*)ws;
    Meta*     meta     = (Meta*)(ws + partBytes);

    chunk_min<<<Bn * G, TPB, 0, stream>>>(mesh_V, mesh_FN, mesh_F, points,
                                          (const unsigned char*)eflag,
                                          partials, meta);
    point_reduce<<<(Bn * Pn) / 128, 128, 0, stream>>>(partials,
                                                      (const unsigned char*)eflag,
                                                      (const int*)eflag, meta, out);
}